// Round 1
// baseline (255.656 us; speedup 1.0000x reference)
//
#include <hip/hip_runtime.h>

#define HH 256
#define WW 256
#define CC 64
#define KK 9
#define OO 64
#define OG 32   // output channels per thread (2 groups)

// Transpose weight (O, C, 3, 3) -> wt[k][i][o] so the o-inner weights are
// contiguous (scalar s_load_dwordx16-friendly).
__global__ void wtrans_kernel(const float* __restrict__ w, float* __restrict__ wt) {
    int t = blockIdx.x * blockDim.x + threadIdx.x;
    if (t >= KK * CC * OO) return;
    int o = t & (OO - 1);
    int i = (t >> 6) & (CC - 1);
    int k = t >> 12;
    wt[t] = w[(o * CC + i) * KK + k];
}

// TR = true: wsrc is wt[k][i][o] (transposed). TR = false: wsrc is original
// weight[o][i][k] (fallback if ws_size too small).
template <bool TR>
__global__ __launch_bounds__(256, 4) void dcn_kernel(
    const float* __restrict__ x, const float* __restrict__ wsrc,
    const float* __restrict__ offset, const float* __restrict__ mask,
    float* __restrict__ out)
{
    const int w  = threadIdx.x;        // 0..255 (= W)
    const int bh = blockIdx.x;         // b*H + h
    const int g  = blockIdx.y;         // o-group, 0..1
    const int b  = bh >> 8;
    const int h  = bh & 255;

    float acc[OG];
    #pragma unroll
    for (int o = 0; o < OG; ++o) acc[o] = 0.f;

    const int HW = HH * WW;
    const float* xb = x + b * CC * HW;
    const int sp    = h * WW + w;
    const int obase = b * (2 * KK) * HW + sp;
    const int mbase = b * KK * HW + sp;

    #pragma unroll 1
    for (int k = 0; k < KK; ++k) {
        const int ky = k / 3, kx = k % 3;
        const float oy = offset[obase + (2 * k) * HW];
        const float ox = offset[obase + (2 * k + 1) * HW];
        const float m  = mask[mbase + k * HW];

        const float py = oy + (float)(h - 1 + ky);
        const float px = ox + (float)(w - 1 + kx);
        const float y0f = floorf(py), x0f = floorf(px);
        const float dy = py - y0f, dx = px - x0f;
        const int y0 = (int)y0f, x0 = (int)x0f;
        const int y1 = y0 + 1,  x1 = x0 + 1;

        const bool vy0 = (y0 >= 0) && (y0 < HH);
        const bool vy1 = (y1 >= 0) && (y1 < HH);
        const bool vx0 = (x0 >= 0) && (x0 < WW);
        const bool vx1 = (x1 >= 0) && (x1 < WW);

        const int y0c = min(max(y0, 0), HH - 1);
        const int y1c = min(max(y1, 0), HH - 1);
        const int x0c = min(max(x0, 0), WW - 1);
        const int x1c = min(max(x1, 0), WW - 1);
        const int i00 = y0c * WW + x0c, i01 = y0c * WW + x1c;
        const int i10 = y1c * WW + x0c, i11 = y1c * WW + x1c;

        // mask premultiplied into the 4 bilinear coefs; invalid corners -> 0
        const float c00 = (1.f - dy) * (1.f - dx) * m * ((vy0 && vx0) ? 1.f : 0.f);
        const float c01 = (1.f - dy) * dx        * m * ((vy0 && vx1) ? 1.f : 0.f);
        const float c10 = dy        * (1.f - dx) * m * ((vy1 && vx0) ? 1.f : 0.f);
        const float c11 = dy        * dx         * m * ((vy1 && vx1) ? 1.f : 0.f);

        const float* wk = TR ? (wsrc + k * CC * OO + g * OG) : wsrc;
        const float* xi = xb;
        #pragma unroll 4
        for (int i = 0; i < CC; ++i) {
            const float v00 = xi[i00], v01 = xi[i01];
            const float v10 = xi[i10], v11 = xi[i11];
            const float val = c00 * v00 + c01 * v01 + c10 * v10 + c11 * v11;
            if (TR) {
                const float* wo = wk + i * OO;   // wave-uniform -> s_load
                #pragma unroll
                for (int o = 0; o < OG; ++o)
                    acc[o] = fmaf(val, wo[o], acc[o]);
            } else {
                #pragma unroll
                for (int o = 0; o < OG; ++o)
                    acc[o] = fmaf(val, wk[((g * OG + o) * CC + i) * KK + k], acc[o]);
            }
            xi += HW;
        }
    }

    float* op = out + (b * OO + g * OG) * HW + sp;
    #pragma unroll
    for (int o = 0; o < OG; ++o) op[o * HW] = acc[o];
}

extern "C" void kernel_launch(void* const* d_in, const int* in_sizes, int n_in,
                              void* d_out, int out_size, void* d_ws, size_t ws_size,
                              hipStream_t stream) {
    const float* x      = (const float*)d_in[0];
    const float* weight = (const float*)d_in[1];
    const float* offset = (const float*)d_in[2];
    const float* mask   = (const float*)d_in[3];
    float* out = (float*)d_out;

    const size_t wt_bytes = (size_t)KK * CC * OO * sizeof(float);
    dim3 grid(2 * HH, OO / OG);  // (b*H, o-group)

    if (ws_size >= wt_bytes) {
        float* wt = (float*)d_ws;
        wtrans_kernel<<<(KK * CC * OO + 255) / 256, 256, 0, stream>>>(weight, wt);
        dcn_kernel<true><<<grid, 256, 0, stream>>>(x, wt, offset, mask, out);
    } else {
        dcn_kernel<false><<<grid, 256, 0, stream>>>(x, weight, offset, mask, out);
    }
}

// Round 2
// 195.258 us; speedup vs baseline: 1.3093x; 1.3093x over previous
//
#include <hip/hip_runtime.h>

#define HH 256
#define WW 256
#define CC 64
#define KT 9
#define OO 64
#define HW (HH * WW)

typedef __bf16 bf16x8 __attribute__((ext_vector_type(8)));
typedef float  f32x4  __attribute__((ext_vector_type(4)));

// ---------------------------------------------------------------------------
// Prep: weight (O=64, C=64, 3, 3) fp32  ->  BL bf16 in MFMA B-frag order.
// B-frag for (tap k, kstep s, ntile u): lane l=(q*16+n) holds
// B[kdim = s*32+q*8+j][o = u*16+n], j=0..7 contiguous -> one dwordx4/lane.
// flat = (((k*2+s)*4+u)*64 + lane)*8 + j
// ---------------------------------------------------------------------------
__global__ void wprep_kernel(const float* __restrict__ w, __bf16* __restrict__ BL) {
    int e = blockIdx.x * 256 + threadIdx.x;
    if (e >= KT * 2 * 4 * 64 * 8) return;
    int j    = e & 7;
    int lane = (e >> 3) & 63;
    int u    = (e >> 9) & 3;
    int s    = (e >> 11) & 1;
    int k    = e >> 12;
    int n = lane & 15, q = lane >> 4;
    int c = s * 32 + q * 8 + j;      // input channel (k-dim within tap)
    int o = u * 16 + n;              // output channel
    BL[e] = (__bf16)w[(o * CC + c) * KT + k];
}

// ---------------------------------------------------------------------------
// Fused DCNv2: bilinear-sample A-frags in registers, MFMA against BL.
// Block = 256 thr = 4 waves; block covers 128 pixels (half a W-row).
// Wave covers 32 pixels (2 M-tiles of 16) x all 64 outputs.
// ---------------------------------------------------------------------------
__global__ __launch_bounds__(256, 3) void dcn_mfma_kernel(
    const float* __restrict__ x, const __bf16* __restrict__ BL,
    const float* __restrict__ offset, const float* __restrict__ mask,
    float* __restrict__ out)
{
    // 4 waves * 64 o * 36 f32 (pad 32->36 keeps 16B align + spreads banks)
    __shared__ float lds[4 * 64 * 36];

    // XCD swizzle: phys%8 = XCD (round-robin dispatch); give each XCD a
    // contiguous band of rows for L2 tap-window reuse.
    const int phys    = blockIdx.x;
    const int logical = (phys & 7) * 128 + (phys >> 3);
    const int b    = logical >> 9;
    const int h    = (logical >> 1) & 255;
    const int half = logical & 1;

    const int wv   = threadIdx.x >> 6;   // wave 0..3
    const int lane = threadIdx.x & 63;
    const int m    = lane & 15;          // A-row / B-col index within tile
    const int q    = lane >> 4;          // quad
    const int wbase = half * 128 + wv * 32;   // wave's pixel w-base

    const float* xb   = x + b * CC * HW;          // batch base (uniform)
    const int    cq   = q * 8 * HW;               // per-lane channel base
    const float* offb = offset + b * (2 * KT) * HW + h * WW;
    const float* mkb  = mask   + b * KT * HW + h * WW;

    f32x4 acc[2][4];
    #pragma unroll
    for (int t = 0; t < 2; ++t)
        #pragma unroll
        for (int u = 0; u < 4; ++u)
            acc[t][u] = (f32x4){0.f, 0.f, 0.f, 0.f};

    #pragma unroll 1
    for (int k = 0; k < KT; ++k) {
        const int ky = k / 3, kx = k % 3;

        // B-frags for this tap: 8 coalesced dwordx4 loads (L2-resident)
        bf16x8 Bf[2][4];
        #pragma unroll
        for (int s = 0; s < 2; ++s)
            #pragma unroll
            for (int u = 0; u < 4; ++u)
                Bf[s][u] = *(const bf16x8*)(BL + (((k * 2 + s) * 4 + u) * 64 + lane) * 8);

        #pragma unroll
        for (int t = 0; t < 2; ++t) {
            const int wp = wbase + t * 16 + m;   // this lane's A-pixel w-coord

            const float oy = offb[(2 * k) * HW + wp];
            const float ox = offb[(2 * k + 1) * HW + wp];
            const float mm = mkb[k * HW + wp];

            const float py = oy + (float)(h - 1 + ky);
            const float px = ox + (float)(wp - 1 + kx);
            const float y0f = floorf(py), x0f = floorf(px);
            const float dy = py - y0f, dx = px - x0f;
            const int y0 = (int)y0f, x0 = (int)x0f;
            const int y1 = y0 + 1,  x1 = x0 + 1;

            const bool vy0 = (unsigned)y0 < (unsigned)HH;
            const bool vy1 = (unsigned)y1 < (unsigned)HH;
            const bool vx0 = (unsigned)x0 < (unsigned)WW;
            const bool vx1 = (unsigned)x1 < (unsigned)WW;

            const int y0c = min(max(y0, 0), HH - 1);
            const int y1c = min(max(y1, 0), HH - 1);
            const int x0c = min(max(x0, 0), WW - 1);
            const int x1c = min(max(x1, 0), WW - 1);
            const int i00 = y0c * WW + x0c, i01 = y0c * WW + x1c;
            const int i10 = y1c * WW + x0c, i11 = y1c * WW + x1c;

            const float c00 = (1.f - dy) * (1.f - dx) * mm * ((vy0 && vx0) ? 1.f : 0.f);
            const float c01 = (1.f - dy) * dx        * mm * ((vy0 && vx1) ? 1.f : 0.f);
            const float c10 = dy        * (1.f - dx) * mm * ((vy1 && vx0) ? 1.f : 0.f);
            const float c11 = dy        * dx         * mm * ((vy1 && vx1) ? 1.f : 0.f);

            #pragma unroll
            for (int s = 0; s < 2; ++s) {
                bf16x8 A;
                #pragma unroll
                for (int j = 0; j < 8; ++j) {
                    const int ofs = cq + (s * 32 + j) * HW;   // channel plane
                    const float v00 = xb[ofs + i00];
                    const float v01 = xb[ofs + i01];
                    const float v10 = xb[ofs + i10];
                    const float v11 = xb[ofs + i11];
                    const float v = c00 * v00 + c01 * v01 + c10 * v10 + c11 * v11;
                    A[j] = (__bf16)v;
                }
                #pragma unroll
                for (int u = 0; u < 4; ++u)
                    acc[t][u] = __builtin_amdgcn_mfma_f32_16x16x32_bf16(
                        A, Bf[s][u], acc[t][u], 0, 0, 0);
            }
        }
    }

    // Epilogue: wave-private LDS transpose -> coalesced stores.
    // D-frag: value (t,u,reg) lives at pixel t*16 + q*4 + reg, o = u*16 + m.
    float* ldsw = lds + wv * 64 * 36;
    #pragma unroll
    for (int t = 0; t < 2; ++t)
        #pragma unroll
        for (int u = 0; u < 4; ++u)
            *(f32x4*)(ldsw + (u * 16 + m) * 36 + t * 16 + q * 4) = acc[t][u];

    // same-wave LDS: in-order per wave; compiler inserts lgkmcnt before reads
    float* outb = out + (b * OO) * HW + h * WW + wbase;
    const int p  = lane & 31;
    const int oh = lane >> 5;
    #pragma unroll
    for (int it = 0; it < 32; ++it) {
        const int o = it * 2 + oh;
        outb[o * HW + p] = ldsw[o * 36 + p];
    }
}

// ---------------------------------------------------------------------------
// Fallback (ws too small): round-1 direct fp32 kernel.
// ---------------------------------------------------------------------------
__global__ __launch_bounds__(256, 4) void dcn_fallback_kernel(
    const float* __restrict__ x, const float* __restrict__ wsrc,
    const float* __restrict__ offset, const float* __restrict__ mask,
    float* __restrict__ out)
{
    const int w  = threadIdx.x;
    const int bh = blockIdx.x;
    const int g  = blockIdx.y;
    const int b  = bh >> 8;
    const int h  = bh & 255;

    float acc[32];
    #pragma unroll
    for (int o = 0; o < 32; ++o) acc[o] = 0.f;

    const float* xbp = x + b * CC * HW;
    const int sp    = h * WW + w;
    const int obase = b * (2 * KT) * HW + sp;
    const int mbase = b * KT * HW + sp;

    #pragma unroll 1
    for (int k = 0; k < KT; ++k) {
        const int ky = k / 3, kx = k % 3;
        const float oy = offset[obase + (2 * k) * HW];
        const float ox = offset[obase + (2 * k + 1) * HW];
        const float mm = mask[mbase + k * HW];
        const float py = oy + (float)(h - 1 + ky);
        const float px = ox + (float)(w - 1 + kx);
        const float y0f = floorf(py), x0f = floorf(px);
        const float dy = py - y0f, dx = px - x0f;
        const int y0 = (int)y0f, x0 = (int)x0f;
        const int y1 = y0 + 1,  x1 = x0 + 1;
        const bool vy0 = (unsigned)y0 < (unsigned)HH;
        const bool vy1 = (unsigned)y1 < (unsigned)HH;
        const bool vx0 = (unsigned)x0 < (unsigned)WW;
        const bool vx1 = (unsigned)x1 < (unsigned)WW;
        const int y0c = min(max(y0, 0), HH - 1);
        const int y1c = min(max(y1, 0), HH - 1);
        const int x0c = min(max(x0, 0), WW - 1);
        const int x1c = min(max(x1, 0), WW - 1);
        const int i00 = y0c * WW + x0c, i01 = y0c * WW + x1c;
        const int i10 = y1c * WW + x0c, i11 = y1c * WW + x1c;
        const float c00 = (1.f - dy) * (1.f - dx) * mm * ((vy0 && vx0) ? 1.f : 0.f);
        const float c01 = (1.f - dy) * dx        * mm * ((vy0 && vx1) ? 1.f : 0.f);
        const float c10 = dy        * (1.f - dx) * mm * ((vy1 && vx0) ? 1.f : 0.f);
        const float c11 = dy        * dx         * mm * ((vy1 && vx1) ? 1.f : 0.f);

        const float* xi = xbp;
        #pragma unroll 4
        for (int i = 0; i < CC; ++i) {
            const float val = c00 * xi[i00] + c01 * xi[i01] + c10 * xi[i10] + c11 * xi[i11];
            #pragma unroll
            for (int o = 0; o < 32; ++o)
                acc[o] = fmaf(val, wsrc[((g * 32 + o) * CC + i) * KT + k], acc[o]);
            xi += HW;
        }
    }
    float* op = out + (b * OO + g * 32) * HW + sp;
    #pragma unroll
    for (int o = 0; o < 32; ++o) op[o * HW] = acc[o];
}

extern "C" void kernel_launch(void* const* d_in, const int* in_sizes, int n_in,
                              void* d_out, int out_size, void* d_ws, size_t ws_size,
                              hipStream_t stream) {
    const float* x      = (const float*)d_in[0];
    const float* weight = (const float*)d_in[1];
    const float* offset = (const float*)d_in[2];
    const float* mask   = (const float*)d_in[3];
    float* out = (float*)d_out;

    const size_t bl_bytes = (size_t)KT * 2 * 4 * 64 * 8 * sizeof(__bf16);  // 73728

    if (ws_size >= bl_bytes) {
        __bf16* BL = (__bf16*)d_ws;
        wprep_kernel<<<144, 256, 0, stream>>>(weight, BL);
        dcn_mfma_kernel<<<1024, 256, 0, stream>>>(x, BL, offset, mask, out);
    } else {
        dim3 grid(2 * HH, 2);
        dcn_fallback_kernel<<<grid, 256, 0, stream>>>(x, weight, offset, mask, out);
    }
}

// Round 3
// 185.587 us; speedup vs baseline: 1.3776x; 1.0521x over previous
//
#include <hip/hip_runtime.h>

#define HH 256
#define WW 256
#define CC 64
#define KT 9
#define OO 64
#define HW (HH * WW)

typedef __bf16 bf16x8 __attribute__((ext_vector_type(8)));
typedef float  f32x4  __attribute__((ext_vector_type(4)));

// ---------------------------------------------------------------------------
// Prep 1: weight (O=64, C=64, 3, 3) fp32 -> BL bf16 in MFMA B-frag order.
// B-frag for (tap k, kstep s, ntile u): lane l=(q*16+n) holds
// B[kdim = s*32+q*8+j][o = u*16+n], j contiguous.
// ---------------------------------------------------------------------------
__global__ void wprep_kernel(const float* __restrict__ w, __bf16* __restrict__ BL) {
    int e = blockIdx.x * 256 + threadIdx.x;
    if (e >= KT * 2 * 4 * 64 * 8) return;
    int j    = e & 7;
    int lane = (e >> 3) & 63;
    int u    = (e >> 9) & 3;
    int s    = (e >> 11) & 1;
    int k    = e >> 12;
    int n = lane & 15, q = lane >> 4;
    int c = s * 32 + q * 8 + j;
    int o = u * 16 + n;
    BL[e] = (__bf16)w[(o * CC + c) * KT + k];
}

// ---------------------------------------------------------------------------
// Prep 2: x NCHW fp32 -> x_t NHWC bf16  (xt[((b*H+y)*W+xcol)*64 + c])
// Block handles (b, h, 64-pixel segment): LDS transpose for coalesced I/O.
// ---------------------------------------------------------------------------
#define XTS 72   // LDS row stride (bf16 elems): 144 B rows keep 16 B align
__global__ __launch_bounds__(256) void xprep_kernel(
    const float* __restrict__ x, __bf16* __restrict__ xt)
{
    __shared__ __align__(16) __bf16 tile[64 * XTS];
    const int blk  = blockIdx.x;          // b*1024 + h*4 + wseg
    const int wseg = blk & 3;
    const int h    = (blk >> 2) & 255;
    const int b    = blk >> 10;
    const int w0   = wseg * 64;
    const int tid  = threadIdx.x;
    const int wl   = tid & 63;
    const int cg   = tid >> 6;            // wave id 0..3 -> channel group

    const float* xp = x + ((size_t)(b * CC + cg * 16) * HH + h) * WW + w0 + wl;
    #pragma unroll
    for (int r = 0; r < 16; ++r)
        tile[wl * XTS + cg * 16 + r] = (__bf16)xp[(size_t)r * HW];
    __syncthreads();

    const int pix = tid >> 2, part = tid & 3;
    const f32x4* src = (const f32x4*)(tile + pix * XTS + part * 16);
    f32x4* dst = (f32x4*)(xt + ((size_t)((b * HH + h) * WW) + w0 + pix) * 64 + part * 16);
    dst[0] = src[0];
    dst[1] = src[1];
}

// ---------------------------------------------------------------------------
// Main: bilinear-sample A-frags from NHWC bf16 xt (dwordx4 gathers), MFMA.
// Block = 4 waves = 128 pixels (half row); wave = 32 pixels x 64 outputs.
// ---------------------------------------------------------------------------
__global__ __launch_bounds__(256, 4) void dcn_mfma2_kernel(
    const __bf16* __restrict__ xt, const __bf16* __restrict__ BL,
    const float* __restrict__ offset, const float* __restrict__ mask,
    float* __restrict__ out)
{
    __shared__ float lds[4 * 64 * 36];

    const int phys    = blockIdx.x;
    const int logical = (phys & 7) * 128 + (phys >> 3);  // XCD row-band swizzle
    const int b    = logical >> 9;
    const int h    = (logical >> 1) & 255;
    const int half = logical & 1;

    const int wv   = threadIdx.x >> 6;
    const int lane = threadIdx.x & 63;
    const int m    = lane & 15;
    const int q    = lane >> 4;
    const int wbase = half * 128 + wv * 32;

    const __bf16* xtb = xt + (size_t)b * HW * 64;
    const int    chq  = q * 8;                   // lane channel offset in row
    const float* offb = offset + b * (2 * KT) * HW + h * WW;
    const float* mkb  = mask   + b * KT * HW + h * WW;

    f32x4 acc[2][4];
    #pragma unroll
    for (int t = 0; t < 2; ++t)
        #pragma unroll
        for (int u = 0; u < 4; ++u)
            acc[t][u] = (f32x4){0.f, 0.f, 0.f, 0.f};

    #pragma unroll 1
    for (int k = 0; k < KT; ++k) {
        const int ky = k / 3, kx = k % 3;

        // per-t sampling coefs + corner pixel indices (computed once per k)
        float cf[2][4];
        int   ix[2][4];
        #pragma unroll
        for (int t = 0; t < 2; ++t) {
            const int wp = wbase + t * 16 + m;
            const float oy = offb[(2 * k) * HW + wp];
            const float ox = offb[(2 * k + 1) * HW + wp];
            const float mm = mkb[k * HW + wp];

            const float py = oy + (float)(h - 1 + ky);
            const float px = ox + (float)(wp - 1 + kx);
            const float y0f = floorf(py), x0f = floorf(px);
            const float dy = py - y0f, dx = px - x0f;
            const int y0 = (int)y0f, x0 = (int)x0f;
            const int y1 = y0 + 1,  x1 = x0 + 1;

            const bool vy0 = (unsigned)y0 < (unsigned)HH;
            const bool vy1 = (unsigned)y1 < (unsigned)HH;
            const bool vx0 = (unsigned)x0 < (unsigned)WW;
            const bool vx1 = (unsigned)x1 < (unsigned)WW;

            const int y0c = min(max(y0, 0), HH - 1);
            const int y1c = min(max(y1, 0), HH - 1);
            const int x0c = min(max(x0, 0), WW - 1);
            const int x1c = min(max(x1, 0), WW - 1);

            ix[t][0] = y0c * WW + x0c;  ix[t][1] = y0c * WW + x1c;
            ix[t][2] = y1c * WW + x0c;  ix[t][3] = y1c * WW + x1c;
            cf[t][0] = (1.f - dy) * (1.f - dx) * mm * ((vy0 && vx0) ? 1.f : 0.f);
            cf[t][1] = (1.f - dy) * dx        * mm * ((vy0 && vx1) ? 1.f : 0.f);
            cf[t][2] = dy        * (1.f - dx) * mm * ((vy1 && vx0) ? 1.f : 0.f);
            cf[t][3] = dy        * dx         * mm * ((vy1 && vx1) ? 1.f : 0.f);
        }

        #pragma unroll
        for (int s = 0; s < 2; ++s) {
            // B-frags for this s-half: 4 coalesced dwordx4 (L1-resident)
            bf16x8 Bf[4];
            #pragma unroll
            for (int u = 0; u < 4; ++u)
                Bf[u] = *(const bf16x8*)(BL + (((k * 2 + s) * 4 + u) * 64 + lane) * 8);

            #pragma unroll
            for (int t = 0; t < 2; ++t) {
                // 4 corner gathers: one dwordx4 each (8 bf16 channels)
                bf16x8 g0 = *(const bf16x8*)(xtb + (size_t)ix[t][0] * 64 + s * 32 + chq);
                bf16x8 g1 = *(const bf16x8*)(xtb + (size_t)ix[t][1] * 64 + s * 32 + chq);
                bf16x8 g2 = *(const bf16x8*)(xtb + (size_t)ix[t][2] * 64 + s * 32 + chq);
                bf16x8 g3 = *(const bf16x8*)(xtb + (size_t)ix[t][3] * 64 + s * 32 + chq);

                bf16x8 A;
                #pragma unroll
                for (int j = 0; j < 8; ++j) {
                    const float v = cf[t][0] * (float)g0[j] + cf[t][1] * (float)g1[j]
                                  + cf[t][2] * (float)g2[j] + cf[t][3] * (float)g3[j];
                    A[j] = (__bf16)v;
                }
                #pragma unroll
                for (int u = 0; u < 4; ++u)
                    acc[t][u] = __builtin_amdgcn_mfma_f32_16x16x32_bf16(
                        A, Bf[u], acc[t][u], 0, 0, 0);
            }
        }
    }

    // Epilogue: wave-private LDS transpose -> coalesced stores.
    float* ldsw = lds + wv * 64 * 36;
    #pragma unroll
    for (int t = 0; t < 2; ++t)
        #pragma unroll
        for (int u = 0; u < 4; ++u)
            *(f32x4*)(ldsw + (u * 16 + m) * 36 + t * 16 + q * 4) = acc[t][u];

    float* outb = out + (size_t)(b * OO) * HW + h * WW + wbase;
    const int p  = lane & 31;
    const int oh = lane >> 5;
    #pragma unroll
    for (int it = 0; it < 32; ++it) {
        const int o = it * 2 + oh;
        outb[(size_t)o * HW + p] = ldsw[o * 36 + p];
    }
}

// ---------------------------------------------------------------------------
// Fallback (ws fits only BL): round-2 kernel, fp32 NCHW gathers.
// ---------------------------------------------------------------------------
__global__ __launch_bounds__(256, 3) void dcn_mfma_kernel(
    const float* __restrict__ x, const __bf16* __restrict__ BL,
    const float* __restrict__ offset, const float* __restrict__ mask,
    float* __restrict__ out)
{
    __shared__ float lds[4 * 64 * 36];
    const int phys    = blockIdx.x;
    const int logical = (phys & 7) * 128 + (phys >> 3);
    const int b    = logical >> 9;
    const int h    = (logical >> 1) & 255;
    const int half = logical & 1;
    const int wv   = threadIdx.x >> 6;
    const int lane = threadIdx.x & 63;
    const int m    = lane & 15;
    const int q    = lane >> 4;
    const int wbase = half * 128 + wv * 32;

    const float* xb   = x + (size_t)b * CC * HW;
    const int    cq   = q * 8 * HW;
    const float* offb = offset + b * (2 * KT) * HW + h * WW;
    const float* mkb  = mask   + b * KT * HW + h * WW;

    f32x4 acc[2][4];
    #pragma unroll
    for (int t = 0; t < 2; ++t)
        #pragma unroll
        for (int u = 0; u < 4; ++u)
            acc[t][u] = (f32x4){0.f, 0.f, 0.f, 0.f};

    #pragma unroll 1
    for (int k = 0; k < KT; ++k) {
        const int ky = k / 3, kx = k % 3;
        bf16x8 Bf[2][4];
        #pragma unroll
        for (int s = 0; s < 2; ++s)
            #pragma unroll
            for (int u = 0; u < 4; ++u)
                Bf[s][u] = *(const bf16x8*)(BL + (((k * 2 + s) * 4 + u) * 64 + lane) * 8);

        #pragma unroll
        for (int t = 0; t < 2; ++t) {
            const int wp = wbase + t * 16 + m;
            const float oy = offb[(2 * k) * HW + wp];
            const float ox = offb[(2 * k + 1) * HW + wp];
            const float mm = mkb[k * HW + wp];
            const float py = oy + (float)(h - 1 + ky);
            const float px = ox + (float)(wp - 1 + kx);
            const float y0f = floorf(py), x0f = floorf(px);
            const float dy = py - y0f, dx = px - x0f;
            const int y0 = (int)y0f, x0 = (int)x0f;
            const int y1 = y0 + 1,  x1 = x0 + 1;
            const bool vy0 = (unsigned)y0 < (unsigned)HH;
            const bool vy1 = (unsigned)y1 < (unsigned)HH;
            const bool vx0 = (unsigned)x0 < (unsigned)WW;
            const bool vx1 = (unsigned)x1 < (unsigned)WW;
            const int y0c = min(max(y0, 0), HH - 1);
            const int y1c = min(max(y1, 0), HH - 1);
            const int x0c = min(max(x0, 0), WW - 1);
            const int x1c = min(max(x1, 0), WW - 1);
            const int i00 = y0c * WW + x0c, i01 = y0c * WW + x1c;
            const int i10 = y1c * WW + x0c, i11 = y1c * WW + x1c;
            const float c00 = (1.f - dy) * (1.f - dx) * mm * ((vy0 && vx0) ? 1.f : 0.f);
            const float c01 = (1.f - dy) * dx        * mm * ((vy0 && vx1) ? 1.f : 0.f);
            const float c10 = dy        * (1.f - dx) * mm * ((vy1 && vx0) ? 1.f : 0.f);
            const float c11 = dy        * dx         * mm * ((vy1 && vx1) ? 1.f : 0.f);

            #pragma unroll
            for (int s = 0; s < 2; ++s) {
                bf16x8 A;
                #pragma unroll
                for (int j = 0; j < 8; ++j) {
                    const int ofs = cq + (s * 32 + j) * HW;
                    const float v = c00 * xb[ofs + i00] + c01 * xb[ofs + i01]
                                  + c10 * xb[ofs + i10] + c11 * xb[ofs + i11];
                    A[j] = (__bf16)v;
                }
                #pragma unroll
                for (int u = 0; u < 4; ++u)
                    acc[t][u] = __builtin_amdgcn_mfma_f32_16x16x32_bf16(
                        A, Bf[s][u], acc[t][u], 0, 0, 0);
            }
        }
    }

    float* ldsw = lds + wv * 64 * 36;
    #pragma unroll
    for (int t = 0; t < 2; ++t)
        #pragma unroll
        for (int u = 0; u < 4; ++u)
            *(f32x4*)(ldsw + (u * 16 + m) * 36 + t * 16 + q * 4) = acc[t][u];

    float* outb = out + (size_t)(b * OO) * HW + h * WW + wbase;
    const int p  = lane & 31;
    const int oh = lane >> 5;
    #pragma unroll
    for (int it = 0; it < 32; ++it) {
        const int o = it * 2 + oh;
        outb[(size_t)o * HW + p] = ldsw[o * 36 + p];
    }
}

extern "C" void kernel_launch(void* const* d_in, const int* in_sizes, int n_in,
                              void* d_out, int out_size, void* d_ws, size_t ws_size,
                              hipStream_t stream) {
    const float* x      = (const float*)d_in[0];
    const float* weight = (const float*)d_in[1];
    const float* offset = (const float*)d_in[2];
    const float* mask   = (const float*)d_in[3];
    float* out = (float*)d_out;

    const size_t bl_bytes = (size_t)KT * 2 * 4 * 64 * 8 * sizeof(__bf16);  // 73728
    const size_t xt_bytes = (size_t)2 * HH * WW * 64 * sizeof(__bf16);     // 16 MiB

    if (ws_size >= bl_bytes + xt_bytes) {
        __bf16* BL = (__bf16*)d_ws;
        __bf16* xt = (__bf16*)((char*)d_ws + bl_bytes);   // 128 B-aligned
        wprep_kernel<<<144, 256, 0, stream>>>(weight, BL);
        xprep_kernel<<<2048, 256, 0, stream>>>(x, xt);
        dcn_mfma2_kernel<<<1024, 256, 0, stream>>>(xt, BL, offset, mask, out);
    } else if (ws_size >= bl_bytes) {
        __bf16* BL = (__bf16*)d_ws;
        wprep_kernel<<<144, 256, 0, stream>>>(weight, BL);
        dcn_mfma_kernel<<<1024, 256, 0, stream>>>(x, BL, offset, mask, out);
    }
}

// Round 4
// 178.300 us; speedup vs baseline: 1.4339x; 1.0409x over previous
//
#include <hip/hip_runtime.h>

#define HH 256
#define WW 256
#define CC 64
#define KT 9
#define OO 64
#define HW (HH * WW)

typedef _Float16 f16x8 __attribute__((ext_vector_type(8)));
typedef float    f32x4 __attribute__((ext_vector_type(4)));

// ---------------------------------------------------------------------------
// Prep 1: weight (O,C,3,3) fp32 -> BL f16 in MFMA B-frag order.
// B-frag (tap k, kstep s, ntile u): lane l=(q*16+n) holds
// B[kdim=s*32+q*8+j][o=u*16+n], j contiguous -> one dwordx4/lane.
// ---------------------------------------------------------------------------
__global__ void wprep_kernel(const float* __restrict__ w, _Float16* __restrict__ BL) {
    int e = blockIdx.x * 256 + threadIdx.x;
    if (e >= KT * 2 * 4 * 64 * 8) return;
    int j    = e & 7;
    int lane = (e >> 3) & 63;
    int u    = (e >> 9) & 3;
    int s    = (e >> 11) & 1;
    int k    = e >> 12;
    int n = lane & 15, q = lane >> 4;
    int c = s * 32 + q * 8 + j;
    int o = u * 16 + n;
    BL[e] = (_Float16)w[(o * CC + c) * KT + k];
}

// ---------------------------------------------------------------------------
// Prep 2: x NCHW fp32 -> xt NHWC f16  (xt[((b*H+y)*W+xcol)*64 + c])
// ---------------------------------------------------------------------------
#define XTS 72   // LDS row stride (f16 elems): 144 B rows keep 16 B align
__global__ __launch_bounds__(256) void xprep_kernel(
    const float* __restrict__ x, _Float16* __restrict__ xt)
{
    __shared__ __align__(16) _Float16 tile[64 * XTS];
    const int blk  = blockIdx.x;          // b*1024 + h*4 + wseg
    const int wseg = blk & 3;
    const int h    = (blk >> 2) & 255;
    const int b    = blk >> 10;
    const int w0   = wseg * 64;
    const int tid  = threadIdx.x;
    const int wl   = tid & 63;
    const int cg   = tid >> 6;

    const float* xp = x + ((size_t)(b * CC + cg * 16) * HH + h) * WW + w0 + wl;
    #pragma unroll
    for (int r = 0; r < 16; ++r)
        tile[wl * XTS + cg * 16 + r] = (_Float16)xp[(size_t)r * HW];
    __syncthreads();

    const int pix = tid >> 2, part = tid & 3;
    const f32x4* src = (const f32x4*)(tile + pix * XTS + part * 16);
    f32x4* dst = (f32x4*)(xt + ((size_t)((b * HH + h) * WW) + w0 + pix) * 64 + part * 16);
    dst[0] = src[0];
    dst[1] = src[1];
}

// ---------------------------------------------------------------------------
// Main: f16 NHWC gathers -> packed-f16 interp -> f16 MFMA. No LDS.
// Block = 4 waves = 128 pixels (half row); wave = 32 pixels x 64 outputs.
// Offset/mask loads software-pipelined one tap ahead; gathers batched 8-deep.
// ---------------------------------------------------------------------------
__global__ __launch_bounds__(256, 4) void dcn_mfma3_kernel(
    const _Float16* __restrict__ xt, const _Float16* __restrict__ BL,
    const float* __restrict__ offset, const float* __restrict__ mask,
    float* __restrict__ out)
{
    const int phys    = blockIdx.x;
    const int logical = (phys & 7) * 128 + (phys >> 3);  // XCD row-band swizzle
    const int b    = logical >> 9;
    const int h    = (logical >> 1) & 255;
    const int half = logical & 1;

    const int lane = threadIdx.x & 63;
    const int wv   = threadIdx.x >> 6;
    const int m    = lane & 15;
    const int q    = lane >> 4;
    const int wbase = half * 128 + wv * 32;

    const _Float16* xtb = xt + (size_t)b * HW * 64;
    const int    chq  = q * 8;
    const float* offb = offset + b * (2 * KT) * HW + h * WW;
    const float* mkb  = mask   + b * KT * HW + h * WW;

    f32x4 acc[2][4];
    #pragma unroll
    for (int t = 0; t < 2; ++t)
        #pragma unroll
        for (int u = 0; u < 4; ++u)
            acc[t][u] = (f32x4){0.f, 0.f, 0.f, 0.f};

    // pipelined offset/mask state (current tap)
    float oyc[2], oxc[2], mmc[2];
    #pragma unroll
    for (int t = 0; t < 2; ++t) {
        const int wp = wbase + t * 16 + m;
        oyc[t] = offb[0 * HW + wp];
        oxc[t] = offb[1 * HW + wp];
        mmc[t] = mkb[wp];
    }

    #pragma unroll 1
    for (int k = 0; k < KT; ++k) {
        // ---- prefetch next tap's offsets/mask (off the critical path) ----
        float oyn[2], oxn[2], mmn[2];
        const int kn = (k < KT - 1) ? k + 1 : k;
        #pragma unroll
        for (int t = 0; t < 2; ++t) {
            const int wp = wbase + t * 16 + m;
            oyn[t] = offb[(2 * kn) * HW + wp];
            oxn[t] = offb[(2 * kn + 1) * HW + wp];
            mmn[t] = mkb[kn * HW + wp];
        }

        const int ky = k / 3, kx = k % 3;

        // ---- coefs (f16) + corner indices from CURRENT offsets ----
        _Float16 ch[2][4];
        int      ix[2][4];
        #pragma unroll
        for (int t = 0; t < 2; ++t) {
            const int wp = wbase + t * 16 + m;
            const float py = oyc[t] + (float)(h - 1 + ky);
            const float px = oxc[t] + (float)(wp - 1 + kx);
            const float y0f = floorf(py), x0f = floorf(px);
            const float dy = py - y0f, dx = px - x0f;
            const int y0 = (int)y0f, x0 = (int)x0f;
            const int y1 = y0 + 1,  x1 = x0 + 1;

            const bool vy0 = (unsigned)y0 < (unsigned)HH;
            const bool vy1 = (unsigned)y1 < (unsigned)HH;
            const bool vx0 = (unsigned)x0 < (unsigned)WW;
            const bool vx1 = (unsigned)x1 < (unsigned)WW;

            const int y0c = min(max(y0, 0), HH - 1);
            const int y1c = min(max(y1, 0), HH - 1);
            const int x0c = min(max(x0, 0), WW - 1);
            const int x1c = min(max(x1, 0), WW - 1);

            ix[t][0] = y0c * WW + x0c;  ix[t][1] = y0c * WW + x1c;
            ix[t][2] = y1c * WW + x0c;  ix[t][3] = y1c * WW + x1c;

            const float mm = mmc[t];
            ch[t][0] = (_Float16)((1.f - dy) * (1.f - dx) * mm * ((vy0 && vx0) ? 1.f : 0.f));
            ch[t][1] = (_Float16)((1.f - dy) * dx        * mm * ((vy0 && vx1) ? 1.f : 0.f));
            ch[t][2] = (_Float16)(dy        * (1.f - dx) * mm * ((vy1 && vx0) ? 1.f : 0.f));
            ch[t][3] = (_Float16)(dy        * dx         * mm * ((vy1 && vx1) ? 1.f : 0.f));
        }

        #pragma unroll
        for (int s = 0; s < 2; ++s) {
            // batch: 4 B-frags + 8 corner gathers issued back-to-back
            f16x8 Bf[4];
            #pragma unroll
            for (int u = 0; u < 4; ++u)
                Bf[u] = *(const f16x8*)(BL + (((k * 2 + s) * 4 + u) * 64 + lane) * 8);

            f16x8 g[2][4];
            #pragma unroll
            for (int t = 0; t < 2; ++t)
                #pragma unroll
                for (int c = 0; c < 4; ++c)
                    g[t][c] = *(const f16x8*)(xtb + (size_t)ix[t][c] * 64 + s * 32 + chq);

            #pragma unroll
            for (int t = 0; t < 2; ++t) {
                // packed v_pk_fma_f16 interp; result is already A-frag layout
                f16x8 A = g[t][0] * ch[t][0];
                A += g[t][1] * ch[t][1];
                A += g[t][2] * ch[t][2];
                A += g[t][3] * ch[t][3];
                #pragma unroll
                for (int u = 0; u < 4; ++u)
                    acc[t][u] = __builtin_amdgcn_mfma_f32_16x16x32_f16(
                        A, Bf[u], acc[t][u], 0, 0, 0);
            }
        }

        oyc[0] = oyn[0]; oyc[1] = oyn[1];
        oxc[0] = oxn[0]; oxc[1] = oxn[1];
        mmc[0] = mmn[0]; mmc[1] = mmn[1];
    }

    // ---- epilogue: direct stores. D-frag: (t,u,reg) -> pixel t*16+q*4+reg,
    // o = u*16+m. Each f32x4 = 4 consecutive pixels; 16 rows x 64 B / instr.
    #pragma unroll
    for (int t = 0; t < 2; ++t)
        #pragma unroll
        for (int u = 0; u < 4; ++u)
            *(f32x4*)(out + (size_t)(b * OO + u * 16 + m) * HW
                          + h * WW + wbase + t * 16 + q * 4) = acc[t][u];
}

// ---------------------------------------------------------------------------
// Fallback (no usable ws): round-1 direct fp32 kernel, original weight layout.
// ---------------------------------------------------------------------------
__global__ __launch_bounds__(256, 4) void dcn_fallback_kernel(
    const float* __restrict__ x, const float* __restrict__ wsrc,
    const float* __restrict__ offset, const float* __restrict__ mask,
    float* __restrict__ out)
{
    const int w  = threadIdx.x;
    const int bh = blockIdx.x;
    const int g  = blockIdx.y;
    const int b  = bh >> 8;
    const int h  = bh & 255;

    float acc[32];
    #pragma unroll
    for (int o = 0; o < 32; ++o) acc[o] = 0.f;

    const float* xbp = x + (size_t)b * CC * HW;
    const int sp    = h * WW + w;
    const int obase = b * (2 * KT) * HW + sp;
    const int mbase = b * KT * HW + sp;

    #pragma unroll 1
    for (int k = 0; k < KT; ++k) {
        const int ky = k / 3, kx = k % 3;
        const float oy = offset[obase + (2 * k) * HW];
        const float ox = offset[obase + (2 * k + 1) * HW];
        const float mm = mask[mbase + k * HW];
        const float py = oy + (float)(h - 1 + ky);
        const float px = ox + (float)(w - 1 + kx);
        const float y0f = floorf(py), x0f = floorf(px);
        const float dy = py - y0f, dx = px - x0f;
        const int y0 = (int)y0f, x0 = (int)x0f;
        const int y1 = y0 + 1,  x1 = x0 + 1;
        const bool vy0 = (unsigned)y0 < (unsigned)HH;
        const bool vy1 = (unsigned)y1 < (unsigned)HH;
        const bool vx0 = (unsigned)x0 < (unsigned)WW;
        const bool vx1 = (unsigned)x1 < (unsigned)WW;
        const int y0c = min(max(y0, 0), HH - 1);
        const int y1c = min(max(y1, 0), HH - 1);
        const int x0c = min(max(x0, 0), WW - 1);
        const int x1c = min(max(x1, 0), WW - 1);
        const int i00 = y0c * WW + x0c, i01 = y0c * WW + x1c;
        const int i10 = y1c * WW + x0c, i11 = y1c * WW + x1c;
        const float c00 = (1.f - dy) * (1.f - dx) * mm * ((vy0 && vx0) ? 1.f : 0.f);
        const float c01 = (1.f - dy) * dx        * mm * ((vy0 && vx1) ? 1.f : 0.f);
        const float c10 = dy        * (1.f - dx) * mm * ((vy1 && vx0) ? 1.f : 0.f);
        const float c11 = dy        * dx         * mm * ((vy1 && vx1) ? 1.f : 0.f);

        const float* xi = xbp;
        #pragma unroll 4
        for (int i = 0; i < CC; ++i) {
            const float val = c00 * xi[i00] + c01 * xi[i01] + c10 * xi[i10] + c11 * xi[i11];
            #pragma unroll
            for (int o = 0; o < 32; ++o)
                acc[o] = fmaf(val, wsrc[((g * 32 + o) * CC + i) * KT + k], acc[o]);
            xi += HW;
        }
    }
    float* op = out + (size_t)(b * OO + g * 32) * HW + sp;
    #pragma unroll
    for (int o = 0; o < 32; ++o) op[(size_t)o * HW] = acc[o];
}

extern "C" void kernel_launch(void* const* d_in, const int* in_sizes, int n_in,
                              void* d_out, int out_size, void* d_ws, size_t ws_size,
                              hipStream_t stream) {
    const float* x      = (const float*)d_in[0];
    const float* weight = (const float*)d_in[1];
    const float* offset = (const float*)d_in[2];
    const float* mask   = (const float*)d_in[3];
    float* out = (float*)d_out;

    const size_t bl_bytes = (size_t)KT * 2 * 4 * 64 * 8 * sizeof(_Float16);  // 73728
    const size_t xt_bytes = (size_t)2 * HH * WW * 64 * sizeof(_Float16);     // 16 MiB

    if (ws_size >= bl_bytes + xt_bytes) {
        _Float16* BL = (_Float16*)d_ws;
        _Float16* xt = (_Float16*)((char*)d_ws + bl_bytes);
        wprep_kernel<<<144, 256, 0, stream>>>(weight, BL);
        xprep_kernel<<<2048, 256, 0, stream>>>(x, xt);
        dcn_mfma3_kernel<<<1024, 256, 0, stream>>>(xt, BL, offset, mask, out);
    } else {
        dim3 grid(2 * HH, 2);
        dcn_fallback_kernel<<<grid, 256, 0, stream>>>(x, weight, offset, mask, out);
    }
}